// Round 1
// baseline (315.599 us; speedup 1.0000x reference)
//
#include <hip/hip_runtime.h>
#include <math.h>

#define E 128
#define NEI 64
#define KTOP 64
#define THREE_E 384

__device__ __forceinline__ float sig_(float x) { return 1.0f / (1.0f + __expf(-x)); }
__device__ __forceinline__ float tanh_(float x) {
    float ax = fabsf(x);
    float e = __expf(-2.0f * ax);
    float r = (1.0f - e) / (1.0f + e);
    return copysignf(r, x);
}

// ---------------- precompute: rank of each relation by score desc ----------------
__global__ void k_mrank(const int* __restrict__ support, const float* __restrict__ cosr,
                        int* __restrict__ rank, int S, int R) {
    __shared__ float sm[256];
    int t = threadIdx.x;
    float v = -INFINITY;
    if (t < R) {
        for (int s = 0; s < S; ++s) v = fmaxf(v, cosr[support[s] * R + t]);
        sm[t] = v;
    }
    __syncthreads();
    if (t < R) {
        int rk = 0;
        for (int r2 = 0; r2 < R; ++r2) {
            float u = sm[r2];
            rk += (u > v) || (u == v && r2 < t);
        }
        rank[t] = rk;
    }
}

// out[r][j] = bias[j] + dot(src[r][:], W[j][:])   (R blocks x 384 threads)
__global__ void k_rowgemm(const float* __restrict__ src, const float* __restrict__ W,
                          const float* __restrict__ bias, float* __restrict__ out) {
    __shared__ float x[E];
    int r = blockIdx.x, j = threadIdx.x;
    if (j < E) x[j] = src[r * E + j];
    __syncthreads();
    float acc = bias[j];
    const float4* w4 = (const float4*)(W + j * E);
#pragma unroll 8
    for (int k = 0; k < E / 4; ++k) {
        float4 wv = w4[k];
        acc += x[4 * k] * wv.x + x[4 * k + 1] * wv.y + x[4 * k + 2] * wv.z + x[4 * k + 3] * wv.w;
    }
    out[r * THREE_E + j] = acc;
}

// emb1[r][e] = gru(gi=G[r], gh=bhh, h=0)
__global__ void k_emb1(const float* __restrict__ G, const float* __restrict__ bhh,
                       float* __restrict__ emb1, int R) {
    int idx = blockIdx.x * blockDim.x + threadIdx.x;
    if (idx >= R * E) return;
    int r = idx >> 7, e = idx & (E - 1);
    float rr = sig_(G[r * THREE_E + e] + bhh[e]);
    float zz = sig_(G[r * THREE_E + E + e] + bhh[E + e]);
    float nn = tanh_(G[r * THREE_E + 2 * E + e] + rr * bhh[2 * E + e]);
    emb1[idx] = (1.0f - zz) * nn;
}

// ---------------- step 1: 64 candidates -> full stable sort ----------------
__global__ void k_s1(const int* __restrict__ query, const int2* __restrict__ edge,
                     const int* __restrict__ rank, const float* __restrict__ emb1,
                     int* __restrict__ ws_ent1, int* __restrict__ ws_rel1,
                     float* __restrict__ o_tree, float* o_emb, float* __restrict__ o_pnode) {
    int b = blockIdx.x, t = threadIdx.x;
    int qh = query[b];
    int2 pr = edge[qh * NEI + t];
    __shared__ int keys[64], s_ent[64], s_rel[64];
    keys[t] = rank[pr.y] * 64 + t;
    __syncthreads();
    int mykey = keys[t], pos = 0;
    for (int u = 0; u < 64; ++u) pos += (keys[u] < mykey);
    s_ent[pos] = pr.x;
    s_rel[pos] = pr.y;
    __syncthreads();
    ws_ent1[b * 64 + t] = s_ent[t];
    ws_rel1[b * 64 + t] = s_rel[t];
    o_tree[(b * 3 + 0) * 64 + t] = (float)s_ent[t];
    o_pnode[(b * 3 + 0) * 64 + t] = (float)qh;
    for (int idx = t; idx < 64 * E; idx += 64) {
        int j = idx >> 7, e = idx & (E - 1);
        o_emb[((b * 3 + 0) * 64 + j) * E + e] = emb1[s_rel[j] * E + e];
    }
}

// ---------------- steps 2 & 3: 4096 candidates -> top-64 + GRU ----------------
template <int STEP>
__global__ __launch_bounds__(256) void k_s23(
    const int2* __restrict__ edge, const int* __restrict__ rank,
    const float* __restrict__ G, const float* __restrict__ GH1,
    const float* __restrict__ emb1, const float* __restrict__ whh,
    const float* __restrict__ bhh,
    const int* __restrict__ ent_prev, const int* __restrict__ rel_prev,
    int* ent_cur, int* rel_cur,
    float* __restrict__ o_tree, float* o_emb,  // o_emb read(row1)+write(row2) in STEP3
    float* __restrict__ o_pidx, float* __restrict__ o_pnode, float* __restrict__ o_rel) {
    int b = blockIdx.x, t = threadIdx.x;
    __shared__ int pe[64], prl[64];
    __shared__ unsigned char rkA[4096];
    __shared__ int hist[256];
    __shared__ int list[4096];
    __shared__ int win_rel[64], win_p[64], win_prel[64];
    __shared__ int s_c, s_lcnt;
    __shared__ float h2t[(STEP == 3) ? (E * 65) : 1];

    if (t < 64) {
        pe[t] = ent_prev[b * 64 + t];
        prl[t] = rel_prev[b * 64 + t];
    }
    hist[t] = 0;
    if (t == 0) {
        s_lcnt = 0;
        s_c = 0x7fffffff;
    }
    if (STEP == 3) {
        for (int idx = t; idx < 64 * E; idx += 256) {
            int p = idx >> 7, k = idx & (E - 1);
            h2t[k * 65 + p] = o_emb[((b * 3 + 1) * 64 + p) * E + k];
        }
    }
    __syncthreads();

    // score/rank all 4096 candidates, histogram ranks
    for (int i = t; i < 4096; i += 256) {
        int p = i >> 6, n = i & 63;
        int2 c = edge[pe[p] * NEI + n];
        unsigned char r = (unsigned char)rank[c.y];
        rkA[i] = r;
        atomicAdd(&hist[r], 1);
    }
    __syncthreads();
    // cutoff rank: smallest c with cumsum(hist[0..c]) >= 64
    {
        int cum = 0;
        for (int r = 0; r <= t; ++r) cum += hist[r];  // t in [0,256)
        if (cum >= 64) atomicMin(&s_c, t);
    }
    __syncthreads();
    int c = s_c;
    // collect all candidates with rank <= c (contains all 64 winners)
    for (int i = t; i < 4096; i += 256) {
        if ((int)rkA[i] <= c) {
            int pos = atomicAdd(&s_lcnt, 1);
            list[pos] = ((int)rkA[i] << 12) | i;
        }
    }
    __syncthreads();
    int lcnt = s_lcnt;
    // ordinal by key = exact jax top_k order (score desc, idx asc)
    for (int e = t; e < lcnt; e += 256) {
        int key = list[e], ord = 0;
        for (int f = 0; f < lcnt; ++f) ord += (list[f] < key);
        if (ord < 64) {
            int i = key & 4095, p = i >> 6, n = i & 63;
            int2 c2 = edge[pe[p] * NEI + n];
            win_rel[ord] = c2.y;
            win_p[ord] = p;
            win_prel[ord] = prl[p];
            o_tree[(b * 3 + (STEP - 1)) * 64 + ord] = (float)c2.x;
            o_pnode[(b * 3 + (STEP - 1)) * 64 + ord] = (float)pe[p];
            o_pidx[(b * 3 + (STEP - 2)) * 64 + ord] = (float)p;
            o_rel[(b * 3 + (STEP - 2)) * 64 + ord] = (float)prl[p];
            if (STEP == 2) {
                ent_cur[b * 64 + ord] = c2.x;
                rel_cur[b * 64 + ord] = c2.y;
            }
            if (STEP == 3) o_rel[(b * 3 + 2) * 64 + ord] = (float)c2.y;
        }
    }
    if (STEP == 3)
        for (int j = t; j < 64; j += 256) o_pidx[(b * 3 + 2) * 64 + j] = (float)j;
    __syncthreads();

    if (STEP == 2) {
        // gh is a pure table lookup (GH1 by parent relation)
        for (int idx = t; idx < 64 * E; idx += 256) {
            int j = idx >> 7, e = idx & (E - 1);
            int rel = win_rel[j], pr = win_prel[j];
            float rr = sig_(G[rel * THREE_E + e] + GH1[pr * THREE_E + e]);
            float zz = sig_(G[rel * THREE_E + E + e] + GH1[pr * THREE_E + E + e]);
            float nn = tanh_(G[rel * THREE_E + 2 * E + e] + rr * GH1[pr * THREE_E + 2 * E + e]);
            float h = emb1[pr * E + e];
            o_emb[((b * 3 + 1) * 64 + j) * E + e] = (1.0f - zz) * nn + zz * h;
        }
    } else {
        // gh = emb2[b, parent] @ whh.T + bhh  (the only real GEMM, fused here)
        int lane = t & 63, w = t >> 6;
        int j = lane;
        int rel = win_rel[j], p = win_p[j];
        for (int eb = 0; eb < 32; eb += 8) {
            int e0 = __builtin_amdgcn_readfirstlane(w * 32 + eb);  // wave-uniform -> s_loads for whh
            float accr[8], accz[8], accn[8];
#pragma unroll
            for (int i2 = 0; i2 < 8; ++i2) {
                accr[i2] = bhh[e0 + i2];
                accz[i2] = bhh[E + e0 + i2];
                accn[i2] = bhh[2 * E + e0 + i2];
            }
            for (int k = 0; k < E; ++k) {
                float h = h2t[k * 65 + p];
#pragma unroll
                for (int i2 = 0; i2 < 8; ++i2) {
                    accr[i2] = fmaf(h, whh[(e0 + i2) * E + k], accr[i2]);
                    accz[i2] = fmaf(h, whh[(E + e0 + i2) * E + k], accz[i2]);
                    accn[i2] = fmaf(h, whh[(2 * E + e0 + i2) * E + k], accn[i2]);
                }
            }
#pragma unroll
            for (int i2 = 0; i2 < 8; ++i2) {
                int e = e0 + i2;
                float rr = sig_(G[rel * THREE_E + e] + accr[i2]);
                float zz = sig_(G[rel * THREE_E + E + e] + accz[i2]);
                float nn = tanh_(G[rel * THREE_E + 2 * E + e] + rr * accn[i2]);
                float h = h2t[e * 65 + p];
                o_emb[((b * 3 + 2) * 64 + j) * E + e] = (1.0f - zz) * nn + zz * h;
            }
        }
    }
}

extern "C" void kernel_launch(void* const* d_in, const int* in_sizes, int n_in,
                              void* d_out, int out_size, void* d_ws, size_t ws_size,
                              hipStream_t stream) {
    const int* query = (const int*)d_in[0];
    const int* support = (const int*)d_in[1];
    const float* cosr = (const float*)d_in[2];
    const int2* edge = (const int2*)d_in[3];
    const float* rel_w = (const float*)d_in[4];
    const float* wih = (const float*)d_in[5];
    const float* whh = (const float*)d_in[6];
    const float* bih = (const float*)d_in[7];
    const float* bhh = (const float*)d_in[8];
    int B = in_sizes[0];          // 512
    int S = in_sizes[1];          // 16
    int R = in_sizes[4] / E;      // 200

    float* out = (float*)d_out;
    size_t o_tree = 0;
    size_t o_emb = (size_t)B * 3 * 64;
    size_t o_pidx = o_emb + (size_t)B * 3 * 64 * E;
    size_t o_pnode = o_pidx + (size_t)B * 3 * 64;
    size_t o_rel = o_pnode + (size_t)B * 3 * 64;

    char* ws = (char*)d_ws;
    int* rank = (int*)ws;   ws += 256 * 4;
    float* G = (float*)ws;  ws += (size_t)R * THREE_E * 4;
    float* emb1 = (float*)ws; ws += (size_t)R * E * 4;
    float* GH1 = (float*)ws;  ws += (size_t)R * THREE_E * 4;
    int* ent1 = (int*)ws;   ws += (size_t)B * 64 * 4;
    int* rel1 = (int*)ws;   ws += (size_t)B * 64 * 4;
    int* ent2 = (int*)ws;   ws += (size_t)B * 64 * 4;
    int* rel2 = (int*)ws;   ws += (size_t)B * 64 * 4;

    k_mrank<<<1, 256, 0, stream>>>(support, cosr, rank, S, R);
    k_rowgemm<<<R, THREE_E, 0, stream>>>(rel_w, wih, bih, G);
    k_emb1<<<(R * E + 255) / 256, 256, 0, stream>>>(G, bhh, emb1, R);
    k_rowgemm<<<R, THREE_E, 0, stream>>>(emb1, whh, bhh, GH1);
    k_s1<<<B, 64, 0, stream>>>(query, edge, rank, emb1, ent1, rel1,
                               out + o_tree, out + o_emb, out + o_pnode);
    k_s23<2><<<B, 256, 0, stream>>>(edge, rank, G, GH1, emb1, whh, bhh,
                                    ent1, rel1, ent2, rel2,
                                    out + o_tree, out + o_emb, out + o_pidx,
                                    out + o_pnode, out + o_rel);
    k_s23<3><<<B, 256, 0, stream>>>(edge, rank, G, GH1, emb1, whh, bhh,
                                    ent2, rel2, nullptr, nullptr,
                                    out + o_tree, out + o_emb, out + o_pidx,
                                    out + o_pnode, out + o_rel);
}

// Round 2
// 123.794 us; speedup vs baseline: 2.5494x; 2.5494x over previous
//
#include <hip/hip_runtime.h>
#include <hip/hip_bf16.h>
#include <math.h>

#define E 128
#define NEI 64
#define KTOP 64
#define THREE_E 384

typedef __attribute__((ext_vector_type(8))) short short8;
typedef __attribute__((ext_vector_type(4))) float f32x4;

__device__ __forceinline__ float sig_(float x) { return 1.0f / (1.0f + __expf(-x)); }
__device__ __forceinline__ float tanh_(float x) {
    float ax = fabsf(x);
    float e = __expf(-2.0f * ax);
    float r = (1.0f - e) / (1.0f + e);
    return copysignf(r, x);
}
__device__ __forceinline__ short bf16_(float x) {
    __hip_bfloat16 h = __float2bfloat16(x);
    return __builtin_bit_cast(short, h);
}

// ---------------- precompute: rank of each relation by score desc ----------------
__global__ void k_mrank(const int* __restrict__ support, const float* __restrict__ cosr,
                        int* __restrict__ rank, int S, int R) {
    __shared__ float sm[256];
    int t = threadIdx.x;
    float v = -INFINITY;
    if (t < R) {
        for (int s = 0; s < S; ++s) v = fmaxf(v, cosr[support[s] * R + t]);
        sm[t] = v;
    }
    __syncthreads();
    if (t < R) {
        int rk = 0;
        for (int r2 = 0; r2 < R; ++r2) {
            float u = sm[r2];
            rk += (u > v) || (u == v && r2 < t);
        }
        rank[t] = rk;
    }
}

// out[r][j] = bias[j] + dot(src[r][:], W[j][:])   (R blocks x 384 threads)
__global__ void k_rowgemm(const float* __restrict__ src, const float* __restrict__ W,
                          const float* __restrict__ bias, float* __restrict__ out) {
    __shared__ float x[E];
    int r = blockIdx.x, j = threadIdx.x;
    if (j < E) x[j] = src[r * E + j];
    __syncthreads();
    float acc = bias[j];
    const float4* w4 = (const float4*)(W + j * E);
#pragma unroll 8
    for (int k = 0; k < E / 4; ++k) {
        float4 wv = w4[k];
        acc += x[4 * k] * wv.x + x[4 * k + 1] * wv.y + x[4 * k + 2] * wv.z + x[4 * k + 3] * wv.w;
    }
    out[r * THREE_E + j] = acc;
}

// emb1[r][e] = gru(gi=G[r], gh=bhh, h=0)
__global__ void k_emb1(const float* __restrict__ G, const float* __restrict__ bhh,
                       float* __restrict__ emb1, int R) {
    int idx = blockIdx.x * blockDim.x + threadIdx.x;
    if (idx >= R * E) return;
    int r = idx >> 7, e = idx & (E - 1);
    float rr = sig_(G[r * THREE_E + e] + bhh[e]);
    float zz = sig_(G[r * THREE_E + E + e] + bhh[E + e]);
    float nn = tanh_(G[r * THREE_E + 2 * E + e] + rr * bhh[2 * E + e]);
    emb1[idx] = (1.0f - zz) * nn;
}

// pack whh into mfma B-fragment lane order (bf16):
// pack[((ct*4+kt)*64 + l)*8 + i] = whh[ct*16 + (l&15)][kt*32 + (l>>4)*8 + i]
__global__ void k_packW(const float* __restrict__ whh, short* __restrict__ pack) {
    int idx = blockIdx.x * 256 + threadIdx.x;  // < 24*4*64*8 = 49152
    int i = idx & 7, l = (idx >> 3) & 63, kt = (idx >> 9) & 3, ct = idx >> 11;
    int er = ct * 16 + (l & 15);
    int k = kt * 32 + (l >> 4) * 8 + i;
    pack[idx] = bf16_(whh[er * E + k]);
}

// ---------------- step 1: 64 candidates -> full stable sort ----------------
__global__ void k_s1(const int* __restrict__ query, const int2* __restrict__ edge,
                     const int* __restrict__ rank, const float* __restrict__ emb1,
                     int* __restrict__ ws_ent1, int* __restrict__ ws_rel1,
                     float* __restrict__ o_tree, float* o_emb, float* __restrict__ o_pnode) {
    int b = blockIdx.x, t = threadIdx.x;
    int qh = query[b];
    int2 pr = edge[qh * NEI + t];
    __shared__ int keys[64], s_ent[64], s_rel[64];
    keys[t] = rank[pr.y] * 64 + t;
    __syncthreads();
    int mykey = keys[t], pos = 0;
    for (int u = 0; u < 64; ++u) pos += (keys[u] < mykey);
    s_ent[pos] = pr.x;
    s_rel[pos] = pr.y;
    __syncthreads();
    ws_ent1[b * 64 + t] = s_ent[t];
    ws_rel1[b * 64 + t] = s_rel[t];
    o_tree[(b * 3 + 0) * 64 + t] = (float)s_ent[t];
    o_pnode[(b * 3 + 0) * 64 + t] = (float)qh;
    for (int idx = t; idx < 64 * E; idx += 64) {
        int j = idx >> 7, e = idx & (E - 1);
        o_emb[((b * 3 + 0) * 64 + j) * E + e] = emb1[s_rel[j] * E + e];
    }
}

// ---------------- steps 2 & 3: 4096 candidates -> top-64 + GRU ----------------
template <int STEP>
__global__ __launch_bounds__(256) void k_s23(
    const int2* __restrict__ edge, const int* __restrict__ rank,
    const float* __restrict__ G, const float* __restrict__ GH1,
    const float* __restrict__ emb1, const short* __restrict__ wpack,
    const float* __restrict__ bhh,
    const int* __restrict__ ent_prev, const int* __restrict__ rel_prev,
    int* ent_cur, int* rel_cur,
    float* __restrict__ o_tree, float* o_emb,  // o_emb read(row1)+write(row2) in STEP3
    float* __restrict__ o_pidx, float* __restrict__ o_pnode, float* __restrict__ o_rel) {
    int b = blockIdx.x, t = threadIdx.x;
    __shared__ int pe[64], prl[64];
    __shared__ unsigned char rkA[4096];
    __shared__ int hist[256];
    __shared__ int list[4096];
    __shared__ int win_rel[64], win_p[64], win_prel[64];
    __shared__ int s_c, s_lcnt;

    if (t < 64) {
        pe[t] = ent_prev[b * 64 + t];
        prl[t] = rel_prev[b * 64 + t];
    }
    hist[t] = 0;
    if (t == 0) {
        s_lcnt = 0;
        s_c = 0x7fffffff;
    }
    __syncthreads();

    // score/rank all 4096 candidates, histogram ranks
    for (int i = t; i < 4096; i += 256) {
        int p = i >> 6, n = i & 63;
        int2 c = edge[pe[p] * NEI + n];
        unsigned char r = (unsigned char)rank[c.y];
        rkA[i] = r;
        atomicAdd(&hist[r], 1);
    }
    __syncthreads();
    // cutoff rank: smallest c with cumsum(hist[0..c]) >= 64
    {
        int cum = 0;
        for (int r = 0; r <= t; ++r) cum += hist[r];  // t in [0,256)
        if (cum >= 64) atomicMin(&s_c, t);
    }
    __syncthreads();
    int c = s_c;
    // collect all candidates with rank <= c (contains all 64 winners)
    for (int i = t; i < 4096; i += 256) {
        if ((int)rkA[i] <= c) {
            int pos = atomicAdd(&s_lcnt, 1);
            list[pos] = ((int)rkA[i] << 12) | i;
        }
    }
    __syncthreads();
    int lcnt = s_lcnt;
    // ordinal by key = exact jax top_k order (score desc, idx asc)
    for (int e = t; e < lcnt; e += 256) {
        int key = list[e], ord = 0;
        for (int f = 0; f < lcnt; ++f) ord += (list[f] < key);
        if (ord < 64) {
            int i = key & 4095, p = i >> 6, n = i & 63;
            int2 c2 = edge[pe[p] * NEI + n];
            win_rel[ord] = c2.y;
            win_p[ord] = p;
            win_prel[ord] = prl[p];
            o_tree[(b * 3 + (STEP - 1)) * 64 + ord] = (float)c2.x;
            o_pnode[(b * 3 + (STEP - 1)) * 64 + ord] = (float)pe[p];
            o_pidx[(b * 3 + (STEP - 2)) * 64 + ord] = (float)p;
            o_rel[(b * 3 + (STEP - 2)) * 64 + ord] = (float)prl[p];
            if (STEP == 2) {
                ent_cur[b * 64 + ord] = c2.x;
                rel_cur[b * 64 + ord] = c2.y;
            }
            if (STEP == 3) o_rel[(b * 3 + 2) * 64 + ord] = (float)c2.y;
        }
    }
    if (STEP == 3)
        for (int j = t; j < 64; j += 256) o_pidx[(b * 3 + 2) * 64 + j] = (float)j;
    __syncthreads();

    if (STEP == 2) {
        // gh is a pure table lookup (GH1 by parent relation)
        for (int idx = t; idx < 64 * E; idx += 256) {
            int j = idx >> 7, e = idx & (E - 1);
            int rel = win_rel[j], pr = win_prel[j];
            float rr = sig_(G[rel * THREE_E + e] + GH1[pr * THREE_E + e]);
            float zz = sig_(G[rel * THREE_E + E + e] + GH1[pr * THREE_E + E + e]);
            float nn = tanh_(G[rel * THREE_E + 2 * E + e] + rr * GH1[pr * THREE_E + 2 * E + e]);
            float h = emb1[pr * E + e];
            o_emb[((b * 3 + 1) * 64 + j) * E + e] = (1.0f - zz) * nn + zz * h;
        }
    } else {
        // gh = emb2[b, parent] @ whh.T + bhh via MFMA.
        // GEMM: gh[j][ecol] = sum_k h2[p(j)][k] * whh[ecol][k], j=0..63, ecol=0..383.
        // Wave w owns output e in [w*32, w*32+32) for all 3 gates.
        int lane = t & 63, w = t >> 6;
        const float* h2base = o_emb + (size_t)((b * 3 + 1) * 64) * E;

        // A-fragments: af[rt][kt], lane l holds A[m=l&15][k=(l>>4)*8+i]
        short8 af[4][4];
#pragma unroll
        for (int rt = 0; rt < 4; ++rt) {
            int p = win_p[rt * 16 + (lane & 15)];
            const float* row = h2base + p * E + (lane >> 4) * 8;
#pragma unroll
            for (int kt = 0; kt < 4; ++kt) {
                float4 v0 = *(const float4*)(row + kt * 32);
                float4 v1 = *(const float4*)(row + kt * 32 + 4);
                short8 a;
                a[0] = bf16_(v0.x); a[1] = bf16_(v0.y); a[2] = bf16_(v0.z); a[3] = bf16_(v0.w);
                a[4] = bf16_(v1.x); a[5] = bf16_(v1.y); a[6] = bf16_(v1.z); a[7] = bf16_(v1.w);
                af[rt][kt] = a;
            }
        }

        f32x4 acc[2][3][4];  // [s][gate][rt]
#pragma unroll
        for (int s = 0; s < 2; ++s)
#pragma unroll
            for (int g = 0; g < 3; ++g)
#pragma unroll
                for (int rt = 0; rt < 4; ++rt) acc[s][g][rt] = (f32x4){0.f, 0.f, 0.f, 0.f};

#pragma unroll
        for (int s = 0; s < 2; ++s) {
#pragma unroll
            for (int g = 0; g < 3; ++g) {
                int ct = g * 8 + w * 2 + s;  // column tile of 16 within 384
#pragma unroll
                for (int kt = 0; kt < 4; ++kt) {
                    short8 bf = *(const short8*)(wpack + ((size_t)(ct * 4 + kt) * 64 + lane) * 8);
#pragma unroll
                    for (int rt = 0; rt < 4; ++rt)
                        acc[s][g][rt] = __builtin_amdgcn_mfma_f32_16x16x32_bf16(
                            af[rt][kt], bf, acc[s][g][rt], 0, 0, 0);
                }
            }
        }

        // Epilogue: D[row=(l>>4)*4+reg][col=l&15]; row->j, col->e within tile.
#pragma unroll
        for (int s = 0; s < 2; ++s) {
#pragma unroll
            for (int rt = 0; rt < 4; ++rt) {
#pragma unroll
                for (int reg = 0; reg < 4; ++reg) {
                    int j = rt * 16 + (lane >> 4) * 4 + reg;
                    int e = w * 32 + s * 16 + (lane & 15);
                    int rel = win_rel[j];
                    float rr = sig_(G[rel * THREE_E + e] + acc[s][0][rt][reg] + bhh[e]);
                    float zz = sig_(G[rel * THREE_E + E + e] + acc[s][1][rt][reg] + bhh[E + e]);
                    float nn = tanh_(G[rel * THREE_E + 2 * E + e] +
                                     rr * (acc[s][2][rt][reg] + bhh[2 * E + e]));
                    int p = win_p[j];
                    float h = h2base[p * E + e];
                    o_emb[((size_t)(b * 3 + 2) * 64 + j) * E + e] = (1.0f - zz) * nn + zz * h;
                }
            }
        }
    }
}

extern "C" void kernel_launch(void* const* d_in, const int* in_sizes, int n_in,
                              void* d_out, int out_size, void* d_ws, size_t ws_size,
                              hipStream_t stream) {
    const int* query = (const int*)d_in[0];
    const int* support = (const int*)d_in[1];
    const float* cosr = (const float*)d_in[2];
    const int2* edge = (const int2*)d_in[3];
    const float* rel_w = (const float*)d_in[4];
    const float* wih = (const float*)d_in[5];
    const float* whh = (const float*)d_in[6];
    const float* bih = (const float*)d_in[7];
    const float* bhh = (const float*)d_in[8];
    int B = in_sizes[0];          // 512
    int S = in_sizes[1];          // 16
    int R = in_sizes[4] / E;      // 200

    float* out = (float*)d_out;
    size_t o_tree = 0;
    size_t o_emb = (size_t)B * 3 * 64;
    size_t o_pidx = o_emb + (size_t)B * 3 * 64 * E;
    size_t o_pnode = o_pidx + (size_t)B * 3 * 64;
    size_t o_rel = o_pnode + (size_t)B * 3 * 64;

    char* ws = (char*)d_ws;
    int* rank = (int*)ws;   ws += 256 * 4;
    float* G = (float*)ws;  ws += (size_t)R * THREE_E * 4;
    float* emb1 = (float*)ws; ws += (size_t)R * E * 4;
    float* GH1 = (float*)ws;  ws += (size_t)R * THREE_E * 4;
    short* wpack = (short*)ws; ws += (size_t)24 * 4 * 64 * 8 * 2;  // 96 KB bf16
    int* ent1 = (int*)ws;   ws += (size_t)B * 64 * 4;
    int* rel1 = (int*)ws;   ws += (size_t)B * 64 * 4;
    int* ent2 = (int*)ws;   ws += (size_t)B * 64 * 4;
    int* rel2 = (int*)ws;   ws += (size_t)B * 64 * 4;

    k_mrank<<<1, 256, 0, stream>>>(support, cosr, rank, S, R);
    k_rowgemm<<<R, THREE_E, 0, stream>>>(rel_w, wih, bih, G);
    k_emb1<<<(R * E + 255) / 256, 256, 0, stream>>>(G, bhh, emb1, R);
    k_rowgemm<<<R, THREE_E, 0, stream>>>(emb1, whh, bhh, GH1);
    k_packW<<<192, 256, 0, stream>>>(whh, wpack);
    k_s1<<<B, 64, 0, stream>>>(query, edge, rank, emb1, ent1, rel1,
                               out + o_tree, out + o_emb, out + o_pnode);
    k_s23<2><<<B, 256, 0, stream>>>(edge, rank, G, GH1, emb1, wpack, bhh,
                                    ent1, rel1, ent2, rel2,
                                    out + o_tree, out + o_emb, out + o_pidx,
                                    out + o_pnode, out + o_rel);
    k_s23<3><<<B, 256, 0, stream>>>(edge, rank, G, GH1, emb1, wpack, bhh,
                                    ent2, rel2, nullptr, nullptr,
                                    out + o_tree, out + o_emb, out + o_pidx,
                                    out + o_pnode, out + o_rel);
}

// Round 3
// 77.770 us; speedup vs baseline: 4.0581x; 1.5918x over previous
//
#include <hip/hip_runtime.h>
#include <hip/hip_bf16.h>
#include <math.h>

#define E 128
#define NEI 64
#define THREE_E 384
#define H2S 132  // padded LDS row stride (floats), 16B-aligned

typedef __attribute__((ext_vector_type(8))) short short8;
typedef __attribute__((ext_vector_type(4))) float f32x4;

__device__ __forceinline__ float sig_(float x) { return 1.0f / (1.0f + __expf(-x)); }
__device__ __forceinline__ float tanh_(float x) {
    float ax = fabsf(x);
    float e = __expf(-2.0f * ax);
    float r = (1.0f - e) / (1.0f + e);
    return copysignf(r, x);
}
__device__ __forceinline__ short bf16_(float x) {
    __hip_bfloat16 h = __float2bfloat16(x);
    return __builtin_bit_cast(short, h);
}

// ---------------- precompute kernels ----------------
__global__ void k_mrank(const int* __restrict__ support, const float* __restrict__ cosr,
                        int* __restrict__ rank, int S, int R) {
    __shared__ float sm[256];
    int t = threadIdx.x;
    float v = -INFINITY;
    if (t < R) {
        for (int s = 0; s < S; ++s) v = fmaxf(v, cosr[support[s] * R + t]);
        sm[t] = v;
    }
    __syncthreads();
    int rk = 0;
    if (t < R) {
        for (int r2 = 0; r2 < R; ++r2) {
            float u = sm[r2];
            rk += (u > v) || (u == v && r2 < t);
        }
    }
    if (t < 256) rank[t] = rk;  // entries >= R are garbage-but-unused
}

__global__ void k_rowgemm(const float* __restrict__ src, const float* __restrict__ W,
                          const float* __restrict__ bias, float* __restrict__ out) {
    __shared__ float x[E];
    int r = blockIdx.x, j = threadIdx.x;
    if (j < E) x[j] = src[r * E + j];
    __syncthreads();
    float acc = bias[j];
    const float4* w4 = (const float4*)(W + j * E);
#pragma unroll 8
    for (int k = 0; k < E / 4; ++k) {
        float4 wv = w4[k];
        acc += x[4 * k] * wv.x + x[4 * k + 1] * wv.y + x[4 * k + 2] * wv.z + x[4 * k + 3] * wv.w;
    }
    out[r * THREE_E + j] = acc;
}

__global__ void k_emb1(const float* __restrict__ G, const float* __restrict__ bhh,
                       float* __restrict__ emb1, int R) {
    int idx = blockIdx.x * blockDim.x + threadIdx.x;
    if (idx >= R * E) return;
    int r = idx >> 7, e = idx & (E - 1);
    float rr = sig_(G[r * THREE_E + e] + bhh[e]);
    float zz = sig_(G[r * THREE_E + E + e] + bhh[E + e]);
    float nn = tanh_(G[r * THREE_E + 2 * E + e] + rr * bhh[2 * E + e]);
    emb1[idx] = (1.0f - zz) * nn;
}

// pack whh into mfma B-fragment lane order (bf16)
__global__ void k_packW(const float* __restrict__ whh, short* __restrict__ pack) {
    int idx = blockIdx.x * 256 + threadIdx.x;  // < 24*4*64*8 = 49152
    int i = idx & 7, l = (idx >> 3) & 63, kt = (idx >> 9) & 3, ct = idx >> 11;
    int er = ct * 16 + (l & 15);
    int k = kt * 32 + (l >> 4) * 8 + i;
    pack[idx] = bf16_(whh[er * E + k]);
}

// ---------------- fused main kernel: steps 1+2+3 per block ----------------
__global__ __launch_bounds__(256) void k_main(
    const int* __restrict__ query, const int2* __restrict__ edge,
    const int* __restrict__ rank, const float* __restrict__ G,
    const float* __restrict__ GH1, const float* __restrict__ emb1,
    const short* __restrict__ wpack, const float* __restrict__ bhh,
    float* __restrict__ o_tree, float* o_emb, float* __restrict__ o_pidx,
    float* __restrict__ o_pnode, float* __restrict__ o_rel) {
    int b = blockIdx.x, t = threadIdx.x;
    __shared__ int rankL[256];
    __shared__ int pe[64], prl[64], npe[64], nprl[64];
    __shared__ int cand[4096];
    __shared__ unsigned char rkA[4096];
    __shared__ int hist[256];
    __shared__ int list[4096];
    __shared__ int win_p[64], win_rel[64], win_prel[64];
    __shared__ int s_c, s_lcnt;
    __shared__ __align__(16) float h2[64][H2S];

    rankL[t] = rank[t];
    // ======== step 1: 64 candidates, full stable sort ========
    int qh = query[b];
    if (t < 64) {
        int2 pr = edge[(size_t)qh * NEI + t];
        cand[t] = (pr.x << 8) | pr.y;
    }
    __syncthreads();
    if (t < 64) list[t] = rankL[cand[t] & 255] * 64 + t;
    __syncthreads();
    if (t < 64) {
        int mykey = list[t], pos = 0;
#pragma unroll
        for (int u = 0; u < 64; ++u) pos += (list[u] < mykey);
        pe[pos] = cand[t] >> 8;
        prl[pos] = cand[t] & 255;
    }
    __syncthreads();
    if (t < 64) {
        o_tree[(b * 3 + 0) * 64 + t] = (float)pe[t];
        o_pnode[(b * 3 + 0) * 64 + t] = (float)qh;
    }
    {   // o_emb row0 = emb1[prl[j]]
        int j = t >> 2, q = t & 3;
        const float4* src = (const float4*)(emb1 + (size_t)prl[j] * E) + q * 8;
        float4* dst = (float4*)(o_emb + ((size_t)(b * 3 + 0) * 64 + j) * E) + q * 8;
#pragma unroll
        for (int v = 0; v < 8; ++v) dst[v] = src[v];
    }

    // ======== select-2: gather (batched) ========
    int p0 = t >> 6, n0 = t & 63;
    int2 cr[16];
#pragma unroll
    for (int u = 0; u < 16; ++u) cr[u] = edge[(size_t)pe[p0 + 4 * u] * NEI + n0];
    hist[t] = 0;
    if (t == 0) s_lcnt = 0;
    __syncthreads();
#pragma unroll
    for (int u = 0; u < 16; ++u) {
        int i = t + 256 * u;
        int rk = rankL[cr[u].y];
        rkA[i] = (unsigned char)rk;
        cand[i] = (cr[u].x << 8) | cr[u].y;
        atomicAdd(&hist[rk], 1);
    }
    __syncthreads();
    if (t < 64) {  // cutoff via wave-0 scan over 256 bins
        int base = 0, c = 255;
        for (int r4 = 0; r4 < 4; ++r4) {
            int sc = hist[r4 * 64 + t];
#pragma unroll
            for (int d = 1; d < 64; d <<= 1) {
                int o = __shfl_up(sc, d, 64);
                if (t >= d) sc += o;
            }
            unsigned long long m = __ballot(base + sc >= 64);
            if (m) { c = r4 * 64 + __ffsll(m) - 1; break; }
            base += __shfl(sc, 63, 64);
        }
        if (t == 0) s_c = c;
    }
    __syncthreads();
    {
        int c = s_c;
#pragma unroll
        for (int u = 0; u < 16; ++u) {
            int i = t + 256 * u;
            int rk = rkA[i];
            if (rk <= c) {
                int pos = atomicAdd(&s_lcnt, 1);
                list[pos] = (rk << 12) | i;
            }
        }
    }
    __syncthreads();
    int lcnt = s_lcnt;
    if (t < 8 && lcnt + t < 4096) list[lcnt + t] = 0x7fffffff;
    __syncthreads();
    {
        int lp = (lcnt + 7) & ~7;
        for (int e = t; e < lcnt; e += 256) {
            int key = list[e], ord = 0;
            for (int f = 0; f < lp; f += 8)
#pragma unroll
                for (int g = 0; g < 8; ++g) ord += (list[f + g] < key);
            if (ord < 64) {
                int i = key & 4095, p = i >> 6;
                int packed = cand[i];
                int ent = packed >> 8, rel = packed & 255;
                win_rel[ord] = rel; win_p[ord] = p; win_prel[ord] = prl[p];
                npe[ord] = ent; nprl[ord] = rel;
                o_tree[(b * 3 + 1) * 64 + ord] = (float)ent;
                o_pnode[(b * 3 + 1) * 64 + ord] = (float)pe[p];
                o_pidx[(b * 3 + 0) * 64 + ord] = (float)p;
                o_rel[(b * 3 + 0) * 64 + ord] = (float)prl[p];
            }
        }
    }
    __syncthreads();
    if (t < 64) { pe[t] = npe[t]; prl[t] = nprl[t]; }
    __syncthreads();

    // ======== select-3: issue gathers NOW (latency hides under GRU-2) ========
    int2 cr3[16];
#pragma unroll
    for (int u = 0; u < 16; ++u) cr3[u] = edge[(size_t)pe[p0 + 4 * u] * NEI + n0];

    // ======== GRU-2: h2 = gru(G[rel], GH1[prel], emb1[prel]) -> LDS + global ========
    {
        int j = t >> 2, q = t & 3;
        int rel = win_rel[j], pr = win_prel[j];
        const float4* Gr = (const float4*)(G + (size_t)rel * THREE_E);
        const float4* Hr = (const float4*)(GH1 + (size_t)pr * THREE_E);
        const float4* h1 = (const float4*)(emb1 + (size_t)pr * E);
        float4* dstg = (float4*)(o_emb + ((size_t)(b * 3 + 1) * 64 + j) * E);
#pragma unroll
        for (int v = 0; v < 8; ++v) {
            int cv = q * 8 + v;
            float4 gr = Gr[cv], gz = Gr[32 + cv], gn = Gr[64 + cv];
            float4 hr = Hr[cv], hz = Hr[32 + cv], hn = Hr[64 + cv];
            float4 h = h1[cv];
            float4 res;
            {
                float rr = sig_(gr.x + hr.x), zz = sig_(gz.x + hz.x);
                float nn = tanh_(gn.x + rr * hn.x);
                res.x = (1.0f - zz) * nn + zz * h.x;
            }
            {
                float rr = sig_(gr.y + hr.y), zz = sig_(gz.y + hz.y);
                float nn = tanh_(gn.y + rr * hn.y);
                res.y = (1.0f - zz) * nn + zz * h.y;
            }
            {
                float rr = sig_(gr.z + hr.z), zz = sig_(gz.z + hz.z);
                float nn = tanh_(gn.z + rr * hn.z);
                res.z = (1.0f - zz) * nn + zz * h.z;
            }
            {
                float rr = sig_(gr.w + hr.w), zz = sig_(gz.w + hz.w);
                float nn = tanh_(gn.w + rr * hn.w);
                res.w = (1.0f - zz) * nn + zz * h.w;
            }
            dstg[cv] = res;
            *(float4*)&h2[j][cv * 4] = res;
        }
    }

    // ======== select-3: finish ========
    hist[t] = 0;
    if (t == 0) s_lcnt = 0;
    __syncthreads();
#pragma unroll
    for (int u = 0; u < 16; ++u) {
        int i = t + 256 * u;
        int rk = rankL[cr3[u].y];
        rkA[i] = (unsigned char)rk;
        cand[i] = (cr3[u].x << 8) | cr3[u].y;
        atomicAdd(&hist[rk], 1);
    }
    __syncthreads();
    if (t < 64) {
        int base = 0, c = 255;
        for (int r4 = 0; r4 < 4; ++r4) {
            int sc = hist[r4 * 64 + t];
#pragma unroll
            for (int d = 1; d < 64; d <<= 1) {
                int o = __shfl_up(sc, d, 64);
                if (t >= d) sc += o;
            }
            unsigned long long m = __ballot(base + sc >= 64);
            if (m) { c = r4 * 64 + __ffsll(m) - 1; break; }
            base += __shfl(sc, 63, 64);
        }
        if (t == 0) s_c = c;
    }
    __syncthreads();
    {
        int c = s_c;
#pragma unroll
        for (int u = 0; u < 16; ++u) {
            int i = t + 256 * u;
            int rk = rkA[i];
            if (rk <= c) {
                int pos = atomicAdd(&s_lcnt, 1);
                list[pos] = (rk << 12) | i;
            }
        }
    }
    __syncthreads();
    lcnt = s_lcnt;
    if (t < 8 && lcnt + t < 4096) list[lcnt + t] = 0x7fffffff;
    __syncthreads();
    {
        int lp = (lcnt + 7) & ~7;
        for (int e = t; e < lcnt; e += 256) {
            int key = list[e], ord = 0;
            for (int f = 0; f < lp; f += 8)
#pragma unroll
                for (int g = 0; g < 8; ++g) ord += (list[f + g] < key);
            if (ord < 64) {
                int i = key & 4095, p = i >> 6;
                int packed = cand[i];
                int ent = packed >> 8, rel = packed & 255;
                win_rel[ord] = rel; win_p[ord] = p; win_prel[ord] = prl[p];
                o_tree[(b * 3 + 2) * 64 + ord] = (float)ent;
                o_pnode[(b * 3 + 2) * 64 + ord] = (float)pe[p];
                o_pidx[(b * 3 + 1) * 64 + ord] = (float)p;
                o_rel[(b * 3 + 1) * 64 + ord] = (float)prl[p];
                o_rel[(b * 3 + 2) * 64 + ord] = (float)rel;
            }
        }
    }
    if (t < 64) o_pidx[(b * 3 + 2) * 64 + t] = (float)t;
    __syncthreads();

    // ======== GRU-3: gh = h2[win_p] @ whh^T + bhh via MFMA (A from LDS) ========
    {
        int lane = t & 63, w = t >> 6;
        short8 af[4][4];
#pragma unroll
        for (int rt = 0; rt < 4; ++rt) {
            int p = win_p[rt * 16 + (lane & 15)];
            const float* row = &h2[p][(lane >> 4) * 8];
#pragma unroll
            for (int kt = 0; kt < 4; ++kt) {
                float4 v0 = *(const float4*)(row + kt * 32);
                float4 v1 = *(const float4*)(row + kt * 32 + 4);
                short8 a;
                a[0] = bf16_(v0.x); a[1] = bf16_(v0.y); a[2] = bf16_(v0.z); a[3] = bf16_(v0.w);
                a[4] = bf16_(v1.x); a[5] = bf16_(v1.y); a[6] = bf16_(v1.z); a[7] = bf16_(v1.w);
                af[rt][kt] = a;
            }
        }
        f32x4 acc[2][3][4];
#pragma unroll
        for (int s = 0; s < 2; ++s)
#pragma unroll
            for (int g = 0; g < 3; ++g)
#pragma unroll
                for (int rt = 0; rt < 4; ++rt) acc[s][g][rt] = (f32x4){0.f, 0.f, 0.f, 0.f};
#pragma unroll
        for (int s = 0; s < 2; ++s)
#pragma unroll
            for (int g = 0; g < 3; ++g) {
                int ct = g * 8 + w * 2 + s;
#pragma unroll
                for (int kt = 0; kt < 4; ++kt) {
                    short8 bf = *(const short8*)(wpack + ((size_t)(ct * 4 + kt) * 64 + lane) * 8);
#pragma unroll
                    for (int rt = 0; rt < 4; ++rt)
                        acc[s][g][rt] = __builtin_amdgcn_mfma_f32_16x16x32_bf16(
                            af[rt][kt], bf, acc[s][g][rt], 0, 0, 0);
                }
            }
#pragma unroll
        for (int s = 0; s < 2; ++s)
#pragma unroll
            for (int rt = 0; rt < 4; ++rt)
#pragma unroll
                for (int reg = 0; reg < 4; ++reg) {
                    int j = rt * 16 + (lane >> 4) * 4 + reg;
                    int e = w * 32 + s * 16 + (lane & 15);
                    int rel = win_rel[j];
                    float rr = sig_(G[rel * THREE_E + e] + acc[s][0][rt][reg] + bhh[e]);
                    float zz = sig_(G[rel * THREE_E + E + e] + acc[s][1][rt][reg] + bhh[E + e]);
                    float nn = tanh_(G[rel * THREE_E + 2 * E + e] +
                                     rr * (acc[s][2][rt][reg] + bhh[2 * E + e]));
                    int p = win_p[j];
                    float h = h2[p][e];
                    o_emb[((size_t)(b * 3 + 2) * 64 + j) * E + e] = (1.0f - zz) * nn + zz * h;
                }
    }
}

extern "C" void kernel_launch(void* const* d_in, const int* in_sizes, int n_in,
                              void* d_out, int out_size, void* d_ws, size_t ws_size,
                              hipStream_t stream) {
    const int* query = (const int*)d_in[0];
    const int* support = (const int*)d_in[1];
    const float* cosr = (const float*)d_in[2];
    const int2* edge = (const int2*)d_in[3];
    const float* rel_w = (const float*)d_in[4];
    const float* wih = (const float*)d_in[5];
    const float* whh = (const float*)d_in[6];
    const float* bih = (const float*)d_in[7];
    const float* bhh = (const float*)d_in[8];
    int B = in_sizes[0];      // 512
    int S = in_sizes[1];      // 16
    int R = in_sizes[4] / E;  // 200

    float* out = (float*)d_out;
    size_t o_tree = 0;
    size_t o_emb = (size_t)B * 3 * 64;
    size_t o_pidx = o_emb + (size_t)B * 3 * 64 * E;
    size_t o_pnode = o_pidx + (size_t)B * 3 * 64;
    size_t o_rel = o_pnode + (size_t)B * 3 * 64;

    char* ws = (char*)d_ws;
    int* rank = (int*)ws;     ws += 256 * 4;
    float* G = (float*)ws;    ws += (size_t)R * THREE_E * 4;
    float* emb1 = (float*)ws; ws += (size_t)R * E * 4;
    float* GH1 = (float*)ws;  ws += (size_t)R * THREE_E * 4;
    short* wpack = (short*)ws; ws += (size_t)24 * 4 * 64 * 8 * 2;

    k_mrank<<<1, 256, 0, stream>>>(support, cosr, rank, S, R);
    k_rowgemm<<<R, THREE_E, 0, stream>>>(rel_w, wih, bih, G);
    k_emb1<<<(R * E + 255) / 256, 256, 0, stream>>>(G, bhh, emb1, R);
    k_rowgemm<<<R, THREE_E, 0, stream>>>(emb1, whh, bhh, GH1);
    k_packW<<<192, 256, 0, stream>>>(whh, wpack);
    k_main<<<B, 256, 0, stream>>>(query, edge, rank, G, GH1, emb1, wpack, bhh,
                                  out + o_tree, out + o_emb, out + o_pidx,
                                  out + o_pnode, out + o_rel);
}

// Round 4
// 59.210 us; speedup vs baseline: 5.3302x; 1.3135x over previous
//
#include <hip/hip_runtime.h>
#include <hip/hip_bf16.h>
#include <math.h>

#define E 128
#define NEI 64
#define THREE_E 384
#define H2S 132  // padded LDS row stride (floats)

typedef __attribute__((ext_vector_type(8))) short short8;
typedef __attribute__((ext_vector_type(4))) float f32x4;

__device__ __forceinline__ float sig_(float x) { return 1.0f / (1.0f + __expf(-x)); }
__device__ __forceinline__ float tanh_(float x) {
    float ax = fabsf(x);
    float e = __expf(-2.0f * ax);
    float r = (1.0f - e) / (1.0f + e);
    return copysignf(r, x);
}
__device__ __forceinline__ short bf16_(float x) {
    __hip_bfloat16 h = __float2bfloat16(x);
    return __builtin_bit_cast(short, h);
}

// ---- kA: independent precomputes fused. blk0=mrank, blk1..R=G rowgemm, rest=packW
__global__ __launch_bounds__(384) void kA(
    const int* __restrict__ support, const float* __restrict__ cosr,
    int* __restrict__ rank, int S, int R,
    const float* __restrict__ rel_w, const float* __restrict__ wih,
    const float* __restrict__ bih, float* __restrict__ G,
    const float* __restrict__ whh, short* __restrict__ wpack) {
    int blk = blockIdx.x, t = threadIdx.x;
    __shared__ float sm[256];
    if (blk == 0) {
        if (t < 256) {
            float v = -INFINITY;
            if (t < R)
                for (int s = 0; s < S; ++s) v = fmaxf(v, cosr[support[s] * R + t]);
            sm[t] = v;
        }
        __syncthreads();
        if (t < 256) {
            int rk = 0;
            if (t < R) {
                float v = sm[t];
                for (int r2 = 0; r2 < R; ++r2) {
                    float u = sm[r2];
                    rk += (u > v) || (u == v && r2 < t);
                }
            }
            rank[t] = rk;
        }
    } else if (blk <= R) {
        int r = blk - 1;
        if (t < E) sm[t] = rel_w[r * E + t];
        __syncthreads();
        float acc = bih[t];
        const float4* w4 = (const float4*)(wih + (size_t)t * E);
#pragma unroll 8
        for (int k = 0; k < E / 4; ++k) {
            float4 wv = w4[k];
            acc += sm[4 * k] * wv.x + sm[4 * k + 1] * wv.y + sm[4 * k + 2] * wv.z +
                   sm[4 * k + 3] * wv.w;
        }
        G[(size_t)r * THREE_E + t] = acc;
    } else {
        int idx = (blk - (R + 1)) * 384 + t;  // < 24*4*64*8 = 49152
        int i = idx & 7, l = (idx >> 3) & 63, kt = (idx >> 9) & 3, ct = idx >> 11;
        int er = ct * 16 + (l & 15);
        int k = kt * 32 + (l >> 4) * 8 + i;
        wpack[idx] = bf16_(whh[(size_t)er * E + k]);
    }
}

// ---- kB: emb1 + GH1 fused (one block per relation)
__global__ __launch_bounds__(384) void kB(
    const float* __restrict__ G, const float* __restrict__ bhh,
    const float* __restrict__ whh, float* __restrict__ emb1,
    float* __restrict__ GH1) {
    int r = blockIdx.x, t = threadIdx.x;
    __shared__ float he[E];
    if (t < E) {
        float rr = sig_(G[(size_t)r * THREE_E + t] + bhh[t]);
        float zz = sig_(G[(size_t)r * THREE_E + E + t] + bhh[E + t]);
        float nn = tanh_(G[(size_t)r * THREE_E + 2 * E + t] + rr * bhh[2 * E + t]);
        float h = (1.0f - zz) * nn;
        he[t] = h;
        emb1[(size_t)r * E + t] = h;
    }
    __syncthreads();
    float acc = bhh[t];
    const float4* w4 = (const float4*)(whh + (size_t)t * E);
#pragma unroll 8
    for (int k = 0; k < E / 4; ++k) {
        float4 wv = w4[k];
        acc += he[4 * k] * wv.x + he[4 * k + 1] * wv.y + he[4 * k + 2] * wv.z +
               he[4 * k + 3] * wv.w;
    }
    GH1[(size_t)r * THREE_E + t] = acc;
}

// ---- fused main kernel: steps 1+2+3, one block (512 thr) per batch ----
__global__ __launch_bounds__(512, 4) void k_main(
    const int* __restrict__ query, const int2* __restrict__ edge,
    const int* __restrict__ rank, const float* __restrict__ G,
    const float* __restrict__ GH1, const float* __restrict__ emb1,
    const short* __restrict__ wpack, const float* __restrict__ bhh,
    float* __restrict__ o_tree, float* o_emb, float* __restrict__ o_pidx,
    float* __restrict__ o_pnode, float* __restrict__ o_rel) {
    int b = blockIdx.x, t = threadIdx.x;
    __shared__ int rankL[256];
    __shared__ int pe[64], prl[64], npe[64], nprl[64];
    __shared__ int cand[4096];
    __shared__ unsigned char rkA[4096];
    __shared__ int hist[256];
    __shared__ int list[4096];
    __shared__ int win_p[64], win_rel[64], win_prel[64];
    __shared__ int s_c, s_lcnt;
    __shared__ __align__(16) float h2[64][H2S];

    if (t < 256) rankL[t] = rank[t];
    // ======== step 1: 64 candidates, full stable sort ========
    int qh = query[b];
    if (t < 64) {
        int2 pr = edge[(size_t)qh * NEI + t];
        cand[t] = (pr.x << 8) | pr.y;
    }
    __syncthreads();
    if (t < 64) list[t] = rankL[cand[t] & 255] * 64 + t;
    __syncthreads();
    if (t < 64) {
        int mykey = list[t], pos = 0;
#pragma unroll
        for (int u = 0; u < 64; ++u) pos += (list[u] < mykey);
        pe[pos] = cand[t] >> 8;
        prl[pos] = cand[t] & 255;
    }
    __syncthreads();

    // ======== select-2: issue gathers early ========
    int p0 = t >> 6, n0 = t & 63;  // p0 in 0..7
    int2 cr[8];
#pragma unroll
    for (int u = 0; u < 8; ++u) cr[u] = edge[(size_t)pe[p0 + 8 * u] * NEI + n0];

    // step-1 outputs (hide gather latency)
    if (t < 64) {
        o_tree[(b * 3 + 0) * 64 + t] = (float)pe[t];
        o_pnode[(b * 3 + 0) * 64 + t] = (float)qh;
    }
    {
        int j = t >> 3, q = t & 7;
        const float4* src = (const float4*)(emb1 + (size_t)prl[j] * E) + q * 4;
        float4* dst = (float4*)(o_emb + ((size_t)(b * 3 + 0) * 64 + j) * E) + q * 4;
#pragma unroll
        for (int v = 0; v < 4; ++v) dst[v] = src[v];
    }
    if (t < 256) hist[t] = 0;
    if (t == 0) s_lcnt = 0;
    __syncthreads();
#pragma unroll
    for (int u = 0; u < 8; ++u) {
        int i = t + 512 * u;
        int rk = rankL[cr[u].y];
        rkA[i] = (unsigned char)rk;
        cand[i] = (cr[u].x << 8) | cr[u].y;
        atomicAdd(&hist[rk], 1);
    }
    __syncthreads();
    if (t < 64) {  // cutoff via wave-0 scan
        int base = 0, c = 255;
        for (int r4 = 0; r4 < 4; ++r4) {
            int sc = hist[r4 * 64 + t];
#pragma unroll
            for (int d = 1; d < 64; d <<= 1) {
                int o = __shfl_up(sc, d, 64);
                if (t >= d) sc += o;
            }
            unsigned long long m = __ballot(base + sc >= 64);
            if (m) { c = r4 * 64 + __ffsll(m) - 1; break; }
            base += __shfl(sc, 63, 64);
        }
        if (t == 0) s_c = c;
    }
    __syncthreads();
    {
        int c = s_c;
#pragma unroll
        for (int u = 0; u < 8; ++u) {
            int i = t + 512 * u;
            if ((int)rkA[i] <= c) {
                int pos = atomicAdd(&s_lcnt, 1);
                list[pos] = ((int)rkA[i] << 12) | i;
            }
        }
    }
    __syncthreads();
    int lcnt = s_lcnt;
    if (t < 8 && lcnt + t < 4096) list[lcnt + t] = 0x7fffffff;
    __syncthreads();
    {
        int lp = (lcnt + 7) & ~7;
        for (int e = t; e < lcnt; e += 512) {
            int key = list[e], ord = 0;
            for (int f = 0; f < lp; f += 8)
#pragma unroll
                for (int g = 0; g < 8; ++g) ord += (list[f + g] < key);
            if (ord < 64) {
                int i = key & 4095, p = i >> 6;
                int packed = cand[i];
                int ent = packed >> 8, rel = packed & 255;
                win_rel[ord] = rel; win_p[ord] = p; win_prel[ord] = prl[p];
                npe[ord] = ent; nprl[ord] = rel;
                o_tree[(b * 3 + 1) * 64 + ord] = (float)ent;
                o_pnode[(b * 3 + 1) * 64 + ord] = (float)pe[p];
                o_pidx[(b * 3 + 0) * 64 + ord] = (float)p;
                o_rel[(b * 3 + 0) * 64 + ord] = (float)prl[p];
            }
        }
    }
    __syncthreads();
    if (t < 64) { pe[t] = npe[t]; prl[t] = nprl[t]; }
    __syncthreads();

    // ======== select-3: issue gathers NOW (hide under GRU-2) ========
    int2 cr3[8];
#pragma unroll
    for (int u = 0; u < 8; ++u) cr3[u] = edge[(size_t)pe[p0 + 8 * u] * NEI + n0];

    // ======== GRU-2 -> h2 (LDS) + o_emb row1 ========
    {
        int j = t >> 3, q = t & 7;
        int rel = win_rel[j], pr = win_prel[j];
        const float4* Gr = (const float4*)(G + (size_t)rel * THREE_E);
        const float4* Hr = (const float4*)(GH1 + (size_t)pr * THREE_E);
        const float4* h1 = (const float4*)(emb1 + (size_t)pr * E);
        float4* dstg = (float4*)(o_emb + ((size_t)(b * 3 + 1) * 64 + j) * E);
#pragma unroll
        for (int v = 0; v < 4; ++v) {
            int cv = q * 4 + v;
            float4 gr = Gr[cv], gz = Gr[32 + cv], gn = Gr[64 + cv];
            float4 hr = Hr[cv], hz = Hr[32 + cv], hn = Hr[64 + cv];
            float4 h = h1[cv];
            float4 res;
            { float rr = sig_(gr.x + hr.x), zz = sig_(gz.x + hz.x);
              float nn = tanh_(gn.x + rr * hn.x); res.x = (1.0f - zz) * nn + zz * h.x; }
            { float rr = sig_(gr.y + hr.y), zz = sig_(gz.y + hz.y);
              float nn = tanh_(gn.y + rr * hn.y); res.y = (1.0f - zz) * nn + zz * h.y; }
            { float rr = sig_(gr.z + hr.z), zz = sig_(gz.z + hz.z);
              float nn = tanh_(gn.z + rr * hn.z); res.z = (1.0f - zz) * nn + zz * h.z; }
            { float rr = sig_(gr.w + hr.w), zz = sig_(gz.w + hz.w);
              float nn = tanh_(gn.w + rr * hn.w); res.w = (1.0f - zz) * nn + zz * h.w; }
            dstg[cv] = res;
            *(float4*)&h2[j][cv * 4] = res;
        }
    }

    // ======== select-3: finish ========
    if (t < 256) hist[t] = 0;
    if (t == 0) s_lcnt = 0;
    __syncthreads();
#pragma unroll
    for (int u = 0; u < 8; ++u) {
        int i = t + 512 * u;
        int rk = rankL[cr3[u].y];
        rkA[i] = (unsigned char)rk;
        cand[i] = (cr3[u].x << 8) | cr3[u].y;
        atomicAdd(&hist[rk], 1);
    }
    __syncthreads();
    if (t < 64) {
        int base = 0, c = 255;
        for (int r4 = 0; r4 < 4; ++r4) {
            int sc = hist[r4 * 64 + t];
#pragma unroll
            for (int d = 1; d < 64; d <<= 1) {
                int o = __shfl_up(sc, d, 64);
                if (t >= d) sc += o;
            }
            unsigned long long m = __ballot(base + sc >= 64);
            if (m) { c = r4 * 64 + __ffsll(m) - 1; break; }
            base += __shfl(sc, 63, 64);
        }
        if (t == 0) s_c = c;
    }
    __syncthreads();
    {
        int c = s_c;
#pragma unroll
        for (int u = 0; u < 8; ++u) {
            int i = t + 512 * u;
            if ((int)rkA[i] <= c) {
                int pos = atomicAdd(&s_lcnt, 1);
                list[pos] = ((int)rkA[i] << 12) | i;
            }
        }
    }
    __syncthreads();
    lcnt = s_lcnt;
    if (t < 8 && lcnt + t < 4096) list[lcnt + t] = 0x7fffffff;
    __syncthreads();
    {
        int lp = (lcnt + 7) & ~7;
        for (int e = t; e < lcnt; e += 512) {
            int key = list[e], ord = 0;
            for (int f = 0; f < lp; f += 8)
#pragma unroll
                for (int g = 0; g < 8; ++g) ord += (list[f + g] < key);
            if (ord < 64) {
                int i = key & 4095, p = i >> 6;
                int packed = cand[i];
                int ent = packed >> 8, rel = packed & 255;
                win_rel[ord] = rel; win_p[ord] = p; win_prel[ord] = prl[p];
                o_tree[(b * 3 + 2) * 64 + ord] = (float)ent;
                o_pnode[(b * 3 + 2) * 64 + ord] = (float)pe[p];
                o_pidx[(b * 3 + 1) * 64 + ord] = (float)p;
                o_rel[(b * 3 + 1) * 64 + ord] = (float)prl[p];
                o_rel[(b * 3 + 2) * 64 + ord] = (float)rel;
            }
        }
    }
    if (t < 64) o_pidx[(b * 3 + 2) * 64 + t] = (float)t;
    __syncthreads();

    // ======== GRU-3: MFMA, wave w owns e in [w*16, w*16+16) across all 3 gates ========
    {
        int lane = t & 63, w = t >> 6;  // w in 0..7
        short8 af[4][4];
#pragma unroll
        for (int rt = 0; rt < 4; ++rt) {
            int p = win_p[rt * 16 + (lane & 15)];
            const float* row = &h2[p][(lane >> 4) * 8];
#pragma unroll
            for (int kt = 0; kt < 4; ++kt) {
                float4 v0 = *(const float4*)(row + kt * 32);
                float4 v1 = *(const float4*)(row + kt * 32 + 4);
                short8 a;
                a[0] = bf16_(v0.x); a[1] = bf16_(v0.y); a[2] = bf16_(v0.z); a[3] = bf16_(v0.w);
                a[4] = bf16_(v1.x); a[5] = bf16_(v1.y); a[6] = bf16_(v1.z); a[7] = bf16_(v1.w);
                af[rt][kt] = a;
            }
        }
        f32x4 acc[3][4];  // [gate][rt]
#pragma unroll
        for (int g = 0; g < 3; ++g)
#pragma unroll
            for (int rt = 0; rt < 4; ++rt) acc[g][rt] = (f32x4){0.f, 0.f, 0.f, 0.f};
#pragma unroll
        for (int g = 0; g < 3; ++g) {
            int ct = g * 8 + w;
#pragma unroll
            for (int kt = 0; kt < 4; ++kt) {
                short8 bf = *(const short8*)(wpack + ((size_t)(ct * 4 + kt) * 64 + lane) * 8);
#pragma unroll
                for (int rt = 0; rt < 4; ++rt)
                    acc[g][rt] = __builtin_amdgcn_mfma_f32_16x16x32_bf16(
                        af[rt][kt], bf, acc[g][rt], 0, 0, 0);
            }
        }
        int e = w * 16 + (lane & 15);
        float b_r = bhh[e], b_z = bhh[E + e], b_n = bhh[2 * E + e];
#pragma unroll
        for (int rt = 0; rt < 4; ++rt)
#pragma unroll
            for (int reg = 0; reg < 4; ++reg) {
                int j = rt * 16 + (lane >> 4) * 4 + reg;
                int rel = win_rel[j];
                float rr = sig_(G[(size_t)rel * THREE_E + e] + acc[0][rt][reg] + b_r);
                float zz = sig_(G[(size_t)rel * THREE_E + E + e] + acc[1][rt][reg] + b_z);
                float nn = tanh_(G[(size_t)rel * THREE_E + 2 * E + e] +
                                 rr * (acc[2][rt][reg] + b_n));
                int p = win_p[j];
                float h = h2[p][e];
                o_emb[((size_t)(b * 3 + 2) * 64 + j) * E + e] = (1.0f - zz) * nn + zz * h;
            }
    }
}

extern "C" void kernel_launch(void* const* d_in, const int* in_sizes, int n_in,
                              void* d_out, int out_size, void* d_ws, size_t ws_size,
                              hipStream_t stream) {
    const int* query = (const int*)d_in[0];
    const int* support = (const int*)d_in[1];
    const float* cosr = (const float*)d_in[2];
    const int2* edge = (const int2*)d_in[3];
    const float* rel_w = (const float*)d_in[4];
    const float* wih = (const float*)d_in[5];
    const float* whh = (const float*)d_in[6];
    const float* bih = (const float*)d_in[7];
    const float* bhh = (const float*)d_in[8];
    int B = in_sizes[0];      // 512
    int S = in_sizes[1];      // 16
    int R = in_sizes[4] / E;  // 200

    float* out = (float*)d_out;
    size_t o_tree = 0;
    size_t o_emb = (size_t)B * 3 * 64;
    size_t o_pidx = o_emb + (size_t)B * 3 * 64 * E;
    size_t o_pnode = o_pidx + (size_t)B * 3 * 64;
    size_t o_rel = o_pnode + (size_t)B * 3 * 64;

    char* ws = (char*)d_ws;
    int* rank = (int*)ws;      ws += 256 * 4;
    float* G = (float*)ws;     ws += (size_t)R * THREE_E * 4;
    float* emb1 = (float*)ws;  ws += (size_t)R * E * 4;
    float* GH1 = (float*)ws;   ws += (size_t)R * THREE_E * 4;
    short* wpack = (short*)ws; ws += (size_t)24 * 4 * 64 * 8 * 2;

    kA<<<1 + R + 128, 384, 0, stream>>>(support, cosr, rank, S, R,
                                        rel_w, wih, bih, G, whh, wpack);
    kB<<<R, 384, 0, stream>>>(G, bhh, whh, emb1, GH1);
    k_main<<<B, 512, 0, stream>>>(query, edge, rank, G, GH1, emb1, wpack, bhh,
                                  out + o_tree, out + o_emb, out + o_pidx,
                                  out + o_pnode, out + o_rel);
}

// Round 5
// 57.289 us; speedup vs baseline: 5.5089x; 1.0335x over previous
//
#include <hip/hip_runtime.h>
#include <hip/hip_bf16.h>
#include <math.h>

#define E 128
#define NEI 64
#define THREE_E 384
#define H2BS 136  // bf16 LDS row stride (shorts): 272B, 16B-multiple

typedef __attribute__((ext_vector_type(8))) short short8;
typedef __attribute__((ext_vector_type(4))) short short4v;
typedef __attribute__((ext_vector_type(4))) float f32x4;

__device__ __forceinline__ float sig_(float x) { return 1.0f / (1.0f + __expf(-x)); }
__device__ __forceinline__ float tanh_(float x) {
    float ax = fabsf(x);
    float e = __expf(-2.0f * ax);
    float r = (1.0f - e) / (1.0f + e);
    return copysignf(r, x);
}
__device__ __forceinline__ short bf16_(float x) {
    __hip_bfloat16 h = __float2bfloat16(x);
    return __builtin_bit_cast(short, h);
}

// ---- kAB: all precompute in one launch.
// blk < R:        G[r] -> emb1[r] -> GH1[r] (chain inside block)
// R <= blk < R+96: wpack (whh in MFMA B-fragment lane order, bf16)
// blk == R+96:    rank
__global__ __launch_bounds__(512) void kAB(
    const int* __restrict__ support, const float* __restrict__ cosr,
    int* __restrict__ rank, int S, int R,
    const float* __restrict__ rel_w, const float* __restrict__ wih,
    const float* __restrict__ bih, float* __restrict__ G,
    const float* __restrict__ whh, const float* __restrict__ bhh,
    float* __restrict__ emb1, float* __restrict__ GH1,
    short* __restrict__ wpack) {
    int blk = blockIdx.x, t = threadIdx.x;
    __shared__ float sm[256];
    __shared__ float grow[THREE_E];
    if (blk < R) {
        int r = blk;
        if (t < E) sm[t] = rel_w[(size_t)r * E + t];
        __syncthreads();
        if (t < THREE_E) {
            float acc = bih[t];
            const float4* w4 = (const float4*)(wih + (size_t)t * E);
#pragma unroll 8
            for (int k = 0; k < E / 4; ++k) {
                float4 wv = w4[k];
                acc += sm[4 * k] * wv.x + sm[4 * k + 1] * wv.y + sm[4 * k + 2] * wv.z +
                       sm[4 * k + 3] * wv.w;
            }
            G[(size_t)r * THREE_E + t] = acc;
            grow[t] = acc;
        }
        __syncthreads();
        if (t < E) {
            float rr = sig_(grow[t] + bhh[t]);
            float zz = sig_(grow[E + t] + bhh[E + t]);
            float nn = tanh_(grow[2 * E + t] + rr * bhh[2 * E + t]);
            float h = (1.0f - zz) * nn;
            sm[t] = h;
            emb1[(size_t)r * E + t] = h;
        }
        __syncthreads();
        if (t < THREE_E) {
            float acc = bhh[t];
            const float4* w4 = (const float4*)(whh + (size_t)t * E);
#pragma unroll 8
            for (int k = 0; k < E / 4; ++k) {
                float4 wv = w4[k];
                acc += sm[4 * k] * wv.x + sm[4 * k + 1] * wv.y + sm[4 * k + 2] * wv.z +
                       sm[4 * k + 3] * wv.w;
            }
            GH1[(size_t)r * THREE_E + t] = acc;
        }
    } else if (blk < R + 96) {
        int idx = (blk - R) * 512 + t;  // < 49152
        int i = idx & 7, l = (idx >> 3) & 63, kt = (idx >> 9) & 3, ct = idx >> 11;
        int er = ct * 16 + (l & 15);
        int k = kt * 32 + (l >> 4) * 8 + i;
        wpack[idx] = bf16_(whh[(size_t)er * E + k]);
    } else {
        if (t < 256) {
            float v = -INFINITY;
            if (t < R)
                for (int s = 0; s < S; ++s) v = fmaxf(v, cosr[support[s] * R + t]);
            sm[t] = v;
        }
        __syncthreads();
        if (t < 256) {
            int rk = 0;
            if (t < R) {
                float v = sm[t];
                for (int r2 = 0; r2 < R; ++r2) {
                    float u = sm[r2];
                    rk += (u > v) || (u == v && r2 < t);
                }
            }
            rank[t] = rk;
        }
    }
}

// ---- fused main: steps 1+2+3 per block, slim LDS ----
__global__ __launch_bounds__(512, 6) void k_main(
    const int* __restrict__ query, const int2* __restrict__ edge,
    const int* __restrict__ rank, const float* __restrict__ G,
    const float* __restrict__ GH1, const float* __restrict__ emb1,
    const short* __restrict__ wpack, const float* __restrict__ bhh,
    float* __restrict__ o_tree, float* __restrict__ o_emb,
    float* __restrict__ o_pidx, float* __restrict__ o_pnode,
    float* __restrict__ o_rel) {
    int b = blockIdx.x, t = threadIdx.x;
    __shared__ int rankL[256];
    __shared__ int pe[64], prl[64], npe[64], nprl[64];
    __shared__ int hist[256];
    __shared__ int list[4096];
    __shared__ int win_p[64], win_rel[64], win_prel[64];
    __shared__ int s_c, s_lcnt;
    __shared__ __align__(16) short h2b[64][H2BS];

    if (t < 256) rankL[t] = rank[t];
    int qh = query[b];
    int e1x = 0, e1y = 0;
    if (t < 64) {
        int2 pr = edge[(size_t)qh * NEI + t];
        e1x = pr.x; e1y = pr.y;
    }
    __syncthreads();
    // ======== step 1: stable sort of 64 ========
    if (t < 64) list[t] = rankL[e1y] * 64 + t;
    __syncthreads();
    if (t < 64) {
        int mykey = list[t], pos = 0;
#pragma unroll
        for (int u = 0; u < 64; ++u) pos += (list[u] < mykey);
        pe[pos] = e1x;
        prl[pos] = e1y;
    }
    if (t < 256) hist[t] = 0;
    if (t == 0) s_lcnt = 0;
    __syncthreads();

    // ======== select-2: gather + hist (rk stays in registers) ========
    int p0 = t >> 6, n0 = t & 63;
    int2 cr[8];
#pragma unroll
    for (int u = 0; u < 8; ++u) cr[u] = edge[(size_t)pe[p0 + 8 * u] * NEI + n0];
    // step-1 outputs overlap the gather latency
    if (t < 64) {
        o_tree[(b * 3 + 0) * 64 + t] = (float)pe[t];
        o_pnode[(b * 3 + 0) * 64 + t] = (float)qh;
    }
    {
        int j = t >> 3, q = t & 7;
        const float4* src = (const float4*)(emb1 + (size_t)prl[j] * E) + q * 4;
        float4* dst = (float4*)(o_emb + ((size_t)(b * 3 + 0) * 64 + j) * E) + q * 4;
#pragma unroll
        for (int v = 0; v < 4; ++v) dst[v] = src[v];
    }
    int rk2[8];
#pragma unroll
    for (int u = 0; u < 8; ++u) {
        rk2[u] = rankL[cr[u].y];
        atomicAdd(&hist[rk2[u]], 1);
    }
    __syncthreads();
    if (t < 64) {  // cutoff via wave-0 scan
        int base = 0, c = 255;
        for (int r4 = 0; r4 < 4; ++r4) {
            int sc = hist[r4 * 64 + t];
#pragma unroll
            for (int d = 1; d < 64; d <<= 1) {
                int o = __shfl_up(sc, d, 64);
                if (t >= d) sc += o;
            }
            unsigned long long m = __ballot(base + sc >= 64);
            if (m) { c = r4 * 64 + __ffsll(m) - 1; break; }
            base += __shfl(sc, 63, 64);
        }
        if (t == 0) s_c = c;
    }
    __syncthreads();
    {
        int c = s_c;
#pragma unroll
        for (int u = 0; u < 8; ++u)
            if (rk2[u] <= c) {
                int pos = atomicAdd(&s_lcnt, 1);
                list[pos] = (rk2[u] << 12) | (t + 512 * u);
            }
    }
    __syncthreads();
    int lcnt = s_lcnt;
    if (t < 8 && lcnt + t < 4096) list[lcnt + t] = 0x7fffffff;
    if (t < 256) hist[t] = 0;  // pre-zero for select-3
    __syncthreads();
    {
        int lp = (lcnt + 7) & ~7;
        for (int e = t; e < lcnt; e += 512) {
            int key = list[e], ord = 0;
            for (int f = 0; f < lp; f += 8)
#pragma unroll
                for (int g = 0; g < 8; ++g) ord += (list[f + g] < key);
            if (ord < 64) {
                int i = key & 4095, p = i >> 6, n = i & 63;
                int2 c2 = edge[(size_t)pe[p] * NEI + n];  // re-gather (L2-hit)
                win_rel[ord] = c2.y; win_p[ord] = p; win_prel[ord] = prl[p];
                npe[ord] = c2.x; nprl[ord] = c2.y;
                o_tree[(b * 3 + 1) * 64 + ord] = (float)c2.x;
                o_pnode[(b * 3 + 1) * 64 + ord] = (float)pe[p];
                o_pidx[(b * 3 + 0) * 64 + ord] = (float)p;
                o_rel[(b * 3 + 0) * 64 + ord] = (float)prl[p];
            }
        }
    }
    if (t == 0) s_lcnt = 0;
    __syncthreads();

    // ======== select-3: gather now (hides under GRU-2) ========
    int2 cr3[8];
#pragma unroll
    for (int u = 0; u < 8; ++u) cr3[u] = edge[(size_t)npe[p0 + 8 * u] * NEI + n0];

    // ======== GRU-2 -> h2b (bf16 LDS) + o_emb row1 (f32, exact) ========
    {
        int j = t >> 3, q = t & 7;
        int rel = win_rel[j], pr = win_prel[j];
        const float4* Gr = (const float4*)(G + (size_t)rel * THREE_E);
        const float4* Hr = (const float4*)(GH1 + (size_t)pr * THREE_E);
        const float4* h1 = (const float4*)(emb1 + (size_t)pr * E);
        float4* dstg = (float4*)(o_emb + ((size_t)(b * 3 + 1) * 64 + j) * E);
#pragma unroll
        for (int v = 0; v < 4; ++v) {
            int cv = q * 4 + v;
            float4 gr = Gr[cv], gz = Gr[32 + cv], gn = Gr[64 + cv];
            float4 hr = Hr[cv], hz = Hr[32 + cv], hn = Hr[64 + cv];
            float4 h = h1[cv];
            float4 res;
            { float rr = sig_(gr.x + hr.x), zz = sig_(gz.x + hz.x);
              float nn = tanh_(gn.x + rr * hn.x); res.x = (1.0f - zz) * nn + zz * h.x; }
            { float rr = sig_(gr.y + hr.y), zz = sig_(gz.y + hz.y);
              float nn = tanh_(gn.y + rr * hn.y); res.y = (1.0f - zz) * nn + zz * h.y; }
            { float rr = sig_(gr.z + hr.z), zz = sig_(gz.z + hz.z);
              float nn = tanh_(gn.z + rr * hn.z); res.z = (1.0f - zz) * nn + zz * h.z; }
            { float rr = sig_(gr.w + hr.w), zz = sig_(gz.w + hz.w);
              float nn = tanh_(gn.w + rr * hn.w); res.w = (1.0f - zz) * nn + zz * h.w; }
            dstg[cv] = res;
            short4v hb = {bf16_(res.x), bf16_(res.y), bf16_(res.z), bf16_(res.w)};
            *(short4v*)&h2b[j][cv * 4] = hb;
        }
    }
    int rk3[8];
#pragma unroll
    for (int u = 0; u < 8; ++u) {
        rk3[u] = rankL[cr3[u].y];
        atomicAdd(&hist[rk3[u]], 1);
    }
    __syncthreads();
    if (t < 64) {
        int base = 0, c = 255;
        for (int r4 = 0; r4 < 4; ++r4) {
            int sc = hist[r4 * 64 + t];
#pragma unroll
            for (int d = 1; d < 64; d <<= 1) {
                int o = __shfl_up(sc, d, 64);
                if (t >= d) sc += o;
            }
            unsigned long long m = __ballot(base + sc >= 64);
            if (m) { c = r4 * 64 + __ffsll(m) - 1; break; }
            base += __shfl(sc, 63, 64);
        }
        if (t == 0) s_c = c;
    }
    __syncthreads();
    {
        int c = s_c;
#pragma unroll
        for (int u = 0; u < 8; ++u)
            if (rk3[u] <= c) {
                int pos = atomicAdd(&s_lcnt, 1);
                list[pos] = (rk3[u] << 12) | (t + 512 * u);
            }
    }
    __syncthreads();
    lcnt = s_lcnt;
    if (t < 8 && lcnt + t < 4096) list[lcnt + t] = 0x7fffffff;
    __syncthreads();
    {
        int lp = (lcnt + 7) & ~7;
        for (int e = t; e < lcnt; e += 512) {
            int key = list[e], ord = 0;
            for (int f = 0; f < lp; f += 8)
#pragma unroll
                for (int g = 0; g < 8; ++g) ord += (list[f + g] < key);
            if (ord < 64) {
                int i = key & 4095, p = i >> 6, n = i & 63;
                int2 c2 = edge[(size_t)npe[p] * NEI + n];
                win_rel[ord] = c2.y; win_p[ord] = p;
                o_tree[(b * 3 + 2) * 64 + ord] = (float)c2.x;
                o_pnode[(b * 3 + 2) * 64 + ord] = (float)npe[p];
                o_pidx[(b * 3 + 1) * 64 + ord] = (float)p;
                o_rel[(b * 3 + 1) * 64 + ord] = (float)nprl[p];
                o_rel[(b * 3 + 2) * 64 + ord] = (float)c2.y;
            }
        }
    }
    if (t < 64) o_pidx[(b * 3 + 2) * 64 + t] = (float)t;
    __syncthreads();

    // ======== GRU-3: MFMA; wave w owns e in [w*16, w*16+16), all 3 gates ========
    {
        int lane = t & 63, w = t >> 6;
        short8 af[4][4];
#pragma unroll
        for (int rt = 0; rt < 4; ++rt) {
            int p = win_p[rt * 16 + (lane & 15)];
            const short* row = &h2b[p][(lane >> 4) * 8];
#pragma unroll
            for (int kt = 0; kt < 4; ++kt) af[rt][kt] = *(const short8*)(row + kt * 32);
        }
        f32x4 acc[3][4];
#pragma unroll
        for (int g = 0; g < 3; ++g)
#pragma unroll
            for (int rt = 0; rt < 4; ++rt) acc[g][rt] = (f32x4){0.f, 0.f, 0.f, 0.f};
#pragma unroll
        for (int g = 0; g < 3; ++g) {
            int ct = g * 8 + w;
#pragma unroll
            for (int kt = 0; kt < 4; ++kt) {
                short8 bf = *(const short8*)(wpack + ((size_t)(ct * 4 + kt) * 64 + lane) * 8);
#pragma unroll
                for (int rt = 0; rt < 4; ++rt)
                    acc[g][rt] = __builtin_amdgcn_mfma_f32_16x16x32_bf16(
                        af[rt][kt], bf, acc[g][rt], 0, 0, 0);
            }
        }
        int e = w * 16 + (lane & 15);
        float b_r = bhh[e], b_z = bhh[E + e], b_n = bhh[2 * E + e];
#pragma unroll
        for (int rt = 0; rt < 4; ++rt)
#pragma unroll
            for (int reg = 0; reg < 4; ++reg) {
                int j = rt * 16 + (lane >> 4) * 4 + reg;
                int rel = win_rel[j];
                float rr = sig_(G[(size_t)rel * THREE_E + e] + acc[0][rt][reg] + b_r);
                float zz = sig_(G[(size_t)rel * THREE_E + E + e] + acc[1][rt][reg] + b_z);
                float nn = tanh_(G[(size_t)rel * THREE_E + 2 * E + e] +
                                 rr * (acc[2][rt][reg] + b_n));
                int p = win_p[j];
                float h = __bfloat162float(__builtin_bit_cast(__hip_bfloat16, h2b[p][e]));
                o_emb[((size_t)(b * 3 + 2) * 64 + j) * E + e] = (1.0f - zz) * nn + zz * h;
            }
    }
}

extern "C" void kernel_launch(void* const* d_in, const int* in_sizes, int n_in,
                              void* d_out, int out_size, void* d_ws, size_t ws_size,
                              hipStream_t stream) {
    const int* query = (const int*)d_in[0];
    const int* support = (const int*)d_in[1];
    const float* cosr = (const float*)d_in[2];
    const int2* edge = (const int2*)d_in[3];
    const float* rel_w = (const float*)d_in[4];
    const float* wih = (const float*)d_in[5];
    const float* whh = (const float*)d_in[6];
    const float* bih = (const float*)d_in[7];
    const float* bhh = (const float*)d_in[8];
    int B = in_sizes[0];      // 512
    int S = in_sizes[1];      // 16
    int R = in_sizes[4] / E;  // 200

    float* out = (float*)d_out;
    size_t o_tree = 0;
    size_t o_emb = (size_t)B * 3 * 64;
    size_t o_pidx = o_emb + (size_t)B * 3 * 64 * E;
    size_t o_pnode = o_pidx + (size_t)B * 3 * 64;
    size_t o_rel = o_pnode + (size_t)B * 3 * 64;

    char* ws = (char*)d_ws;
    int* rank = (int*)ws;      ws += 256 * 4;
    float* G = (float*)ws;     ws += (size_t)R * THREE_E * 4;
    float* emb1 = (float*)ws;  ws += (size_t)R * E * 4;
    float* GH1 = (float*)ws;   ws += (size_t)R * THREE_E * 4;
    short* wpack = (short*)ws; ws += (size_t)24 * 4 * 64 * 8 * 2;

    kAB<<<R + 96 + 1, 512, 0, stream>>>(support, cosr, rank, S, R, rel_w, wih, bih,
                                        G, whh, bhh, emb1, GH1, wpack);
    k_main<<<B, 512, 0, stream>>>(query, edge, rank, G, GH1, emb1, wpack, bhh,
                                  out + o_tree, out + o_emb, out + o_pidx,
                                  out + o_pnode, out + o_rel);
}